// Round 4
// baseline (1605.022 us; speedup 1.0000x reference)
//
#include <hip/hip_runtime.h>
#include <math.h>

#define NN 20000
#define EE 200000
// MUL=128, D=512, EDGE_ATTR=32, HID=32

__device__ __forceinline__ float sspf(float x){
    float sp = (x > 20.f) ? x : log1pf(expf(x));
    return sp - 0.69314718056f;
}

__device__ __forceinline__ void fma8(float* acc, const float* base, float w){
    const float4 a = ((const float4*)base)[0];
    const float4 b = ((const float4*)base)[1];
    acc[0]+=a.x*w; acc[1]+=a.y*w; acc[2]+=a.z*w; acc[3]+=a.w*w;
    acc[4]+=b.x*w; acc[5]+=b.y*w; acc[6]+=b.z*w; acc[7]+=b.w*w;
}

// ---------------- K1: pre irrep_linear -> p1, sdst (p0 consumed in-LDS) ----
__global__ __launch_bounds__(256) void k_pre(
    const float* __restrict__ x, const float* __restrict__ Wp0,
    const float* __restrict__ bp0, const float* __restrict__ Wp1,
    const float* __restrict__ Ws1,
    float* __restrict__ p1, float* __restrict__ sdst)
{
    __shared__ float xl[512][8];    // transposed [feature][node]
    __shared__ float p0l[8][128];
    const int tid = threadIdx.x;
    const int n0 = blockIdx.x * 8;

    for (int it = 0; it < 4; ++it){
        int idx = tid + 256*it;           // 0..1023 float4 slots
        int node = idx >> 7, o4 = idx & 127;
        float4 v = ((const float4*)(x + (size_t)(n0+node)*512))[o4];
        xl[o4*4+0][node]=v.x; xl[o4*4+1][node]=v.y;
        xl[o4*4+2][node]=v.z; xl[o4*4+3][node]=v.w;
    }
    __syncthreads();

    const int j = tid;
    float acc1[8] = {0,0,0,0,0,0,0,0};
    float acc2[8] = {0,0,0,0,0,0,0,0};
    const int o2 = j + 128;               // p1-index in [128,384)
    const int v2 = o2/3, m2 = o2%3;

    if (j < 128){
        for (int u = 0; u < 128; ++u){
            float w1 = Wp0[u*128 + j];
            float w2 = Wp1[u*128 + v2];
            fma8(acc1, &xl[u][0], w1);
            fma8(acc2, &xl[128 + u*3 + m2][0], w2);
        }
        float b = bp0[j];
        #pragma unroll
        for (int n = 0; n < 8; ++n) p0l[n][j] = acc1[n] + b;
    } else {
        const int o1 = j - 128, v1 = o1/3, m1 = o1%3;
        for (int u = 0; u < 128; ++u){
            float w1 = Wp1[u*128 + v1];
            float w2 = Wp1[u*128 + v2];
            fma8(acc1, &xl[128 + u*3 + m1][0], w1);
            fma8(acc2, &xl[128 + u*3 + m2][0], w2);
        }
        #pragma unroll
        for (int n = 0; n < 8; ++n) p1[(size_t)(n0+n)*384 + (j-128)] = acc1[n];
    }
    #pragma unroll
    for (int n = 0; n < 8; ++n) p1[(size_t)(n0+n)*384 + o2] = acc2[n];
    __syncthreads();

    // sdst = p0 @ (Ws1[0:128] + Ws1[128:256])  (the dst-only part of s0@W_s1)
    {
        int n = tid >> 5, h = tid & 31;
        float s = 0.f;
        for (int u = 0; u < 128; ++u){
            float wc = Ws1[u*32 + h] + Ws1[(128+u)*32 + h];
            s += p0l[n][u] * wc;
        }
        sdst[(size_t)(n0+n)*32 + h] = s;
    }
}

// ---------------- K2: gate + node irrep_linear -> self_x -------------------
__global__ __launch_bounds__(256) void k_gate_nd(
    const float* __restrict__ x,
    const float* __restrict__ Wg1, const float* __restrict__ bg1,
    const float* __restrict__ Wg2, const float* __restrict__ bg2,
    const float* __restrict__ Wnd0, const float* __restrict__ bnd0,
    const float* __restrict__ Wnd1,
    float* __restrict__ self_x)
{
    __shared__ float xl[512][8];
    __shared__ float tl[256][8];   // t, then reused for g
    __shared__ float hl[256][8];
    const int tid = threadIdx.x;
    const int n0 = blockIdx.x * 8;

    for (int it = 0; it < 4; ++it){
        int idx = tid + 256*it;
        int node = idx >> 7, o4 = idx & 127;
        float4 v = ((const float4*)(x + (size_t)(n0+node)*512))[o4];
        xl[o4*4+0][node]=v.x; xl[o4*4+1][node]=v.y;
        xl[o4*4+2][node]=v.z; xl[o4*4+3][node]=v.w;
    }
    __syncthreads();

    { // t = [x0, n1]
        int jj = tid;
        if (jj < 128){
            #pragma unroll
            for (int n = 0; n < 8; ++n) tl[jj][n] = xl[jj][n];
        } else {
            int u = jj - 128;
            #pragma unroll
            for (int n = 0; n < 8; ++n){
                float a = xl[128+u*3][n], b = xl[128+u*3+1][n], c = xl[128+u*3+2][n];
                tl[jj][n] = sqrtf((a*a + b*b + c*c) * (1.f/3.f));
            }
        }
    }
    __syncthreads();

    { // h = silu(t @ Wg1 + bg1)
        float acc[8] = {0,0,0,0,0,0,0,0};
        for (int k = 0; k < 256; ++k){
            float w = Wg1[k*256 + tid];
            fma8(acc, &tl[k][0], w);
        }
        float b = bg1[tid];
        #pragma unroll
        for (int n = 0; n < 8; ++n){
            float v = acc[n] + b;
            hl[tid][n] = v / (1.f + expf(-v));
        }
    }
    __syncthreads();

    { // g = h @ Wg2 + bg2  (stored into tl; tl is dead after the barrier)
        float acc[8] = {0,0,0,0,0,0,0,0};
        for (int k = 0; k < 256; ++k){
            float w = Wg2[k*256 + tid];
            fma8(acc, &hl[k][0], w);
        }
        float b = bg2[tid];
        #pragma unroll
        for (int n = 0; n < 8; ++n) tl[tid][n] = acc[n] + b;
    }
    __syncthreads();

    { // xg in-place into xl
        int jj = tid;
        if (jj < 128){
            #pragma unroll
            for (int n = 0; n < 8; ++n) xl[jj][n] = tl[jj][n];
        } else {
            int u = jj - 128;
            #pragma unroll
            for (int n = 0; n < 8; ++n){
                float g1 = tl[128+u][n];
                xl[128+u*3  ][n] *= g1;
                xl[128+u*3+1][n] *= g1;
                xl[128+u*3+2][n] *= g1;
            }
        }
    }
    __syncthreads();

    // nd irrep_linear
    const int j = tid;
    float acc1[8] = {0,0,0,0,0,0,0,0};
    float acc2[8] = {0,0,0,0,0,0,0,0};
    const int o2 = j + 128;
    const int v2 = o2/3, m2 = o2%3;
    if (j < 128){
        for (int u = 0; u < 128; ++u){
            float w1 = Wnd0[u*128 + j];
            float w2 = Wnd1[u*128 + v2];
            fma8(acc1, &xl[u][0], w1);
            fma8(acc2, &xl[128 + u*3 + m2][0], w2);
        }
        float b = bnd0[j];
        #pragma unroll
        for (int n = 0; n < 8; ++n) self_x[(size_t)(n0+n)*512 + j] = acc1[n] + b;
    } else {
        const int o1 = j - 128, v1 = o1/3, m1 = o1%3;
        for (int u = 0; u < 128; ++u){
            float w1 = Wnd1[u*128 + v1];
            float w2 = Wnd1[u*128 + v2];
            fma8(acc1, &xl[128 + u*3 + m1][0], w1);
            fma8(acc2, &xl[128 + u*3 + m2][0], w2);
        }
        #pragma unroll
        for (int n = 0; n < 8; ++n) self_x[(size_t)(n0+n)*512 + j] = acc1[n];
    }
    #pragma unroll
    for (int n = 0; n < 8; ++n) self_x[(size_t)(n0+n)*512 + j + 256] = acc2[n];
}

// ---------------- K3: edge features -> fbuf, sbuf (E x 32 each) ------------
__global__ __launch_bounds__(256) void k_edge_pre(
    const float* __restrict__ p1g, const float* __restrict__ sdst,
    const float* __restrict__ ea, const int* __restrict__ eidx,
    const float* __restrict__ Wf1, const float* __restrict__ Ws1,
    float* __restrict__ fbuf, float* __restrict__ sbuf)
{
    __shared__ float p1d[8][384], p1s[8][384];
    __shared__ float eal[8][32], sdl[8][32];
    __shared__ float ip1l[8][128];
    __shared__ int il[8][2];
    const int tid = threadIdx.x;
    const long e0 = (long)blockIdx.x * 8;

    if (tid < 16){
        int e = tid & 7;
        il[e][tid>>3] = eidx[(size_t)(tid>>3)*EE + e0 + e];
    }
    __syncthreads();

    for (int e = 0; e < 8; ++e){
        int dst = il[e][0], src = il[e][1];
        if (tid < 96)
            ((float4*)p1d[e])[tid] = ((const float4*)(p1g + (size_t)dst*384))[tid];
        else if (tid < 192)
            ((float4*)p1s[e])[tid-96] = ((const float4*)(p1g + (size_t)src*384))[tid-96];
        else if (tid < 200)
            ((float4*)eal[e])[tid-192] = ((const float4*)(ea + (e0+e)*32))[tid-192];
        else if (tid < 208)
            ((float4*)sdl[e])[tid-200] = ((const float4*)(sdst + (size_t)dst*32))[tid-200];
    }
    __syncthreads();

    for (int it = 0; it < 4; ++it){
        int idx = tid + 256*it;
        int e = idx >> 7, u = idx & 127;
        ip1l[e][u] = (p1d[e][u*3]*p1s[e][u*3] + p1d[e][u*3+1]*p1s[e][u*3+1]
                    + p1d[e][u*3+2]*p1s[e][u*3+2]) * (1.f/3.f);
    }
    __syncthreads();

    {
        int e = tid >> 5, h = tid & 31;
        float f = 0.f;
        for (int k = 0; k < 32; ++k) f += eal[e][k] * Wf1[k*32 + h];
        float s = sdl[e][h];
        for (int u = 0; u < 128; ++u) s += ip1l[e][u] * Ws1[(256+u)*32 + h];
        fbuf[(e0+e)*32 + h] = sspf(f);
        sbuf[(e0+e)*32 + h] = sspf(s);
    }
}

// ---------------- CSR build: count, scan, fill -----------------------------
__global__ __launch_bounds__(256) void k_count(
    const int* __restrict__ eidx, int* __restrict__ cnt)
{
    int e = blockIdx.x * 256 + threadIdx.x;
    if (e < EE){
        int d = eidx[e];
        if (d >= 0 && d < NN) atomicAdd(&cnt[d], 1);
    }
}

__global__ __launch_bounds__(256) void k_scan(
    const int* __restrict__ cnt, int* __restrict__ rowptr, int* __restrict__ cur)
{
    __shared__ int part[256];
    const int t = threadIdx.x;
    const int CHUNK = 79;             // 256*79 = 20224 >= 20000
    const int base = t * CHUNK;
    int s = 0;
    for (int i = 0; i < CHUNK; ++i){
        int idx = base + i;
        if (idx < NN) s += cnt[idx];
    }
    part[t] = s;
    __syncthreads();
    for (int off = 1; off < 256; off <<= 1){
        int v = (t >= off) ? part[t-off] : 0;
        __syncthreads();
        part[t] += v;
        __syncthreads();
    }
    int run = (t == 0) ? 0 : part[t-1];
    for (int i = 0; i < CHUNK; ++i){
        int idx = base + i;
        if (idx < NN){
            rowptr[idx] = run;
            cur[idx]    = run;
            run += cnt[idx];
        }
    }
    if (t == 255) rowptr[NN] = run;
}

__global__ __launch_bounds__(256) void k_fill(
    const int* __restrict__ eidx, int* __restrict__ cur, int2* __restrict__ ebuf)
{
    int e = blockIdx.x * 256 + threadIdx.x;
    if (e < EE){
        int dst = eidx[e];
        int src = eidx[EE + e];
        if (dst >= 0 && dst < NN){
            int pos = atomicAdd(&cur[dst], 1);
            if (pos >= 0 && pos < EE) ebuf[pos] = make_int2(e, src);
        }
    }
}

// ---------------- K4 epilogue: apply one edge's weights --------------------
__device__ __forceinline__ void edge_epilogue(
    float2& o0, float* o1a, float* o1b,
    const float2 af[4], const float2 as[4],
    const float* __restrict__ sx, float4 sh, int lane)
{
    float2 w1 = make_float2(af[0].x*as[0].x, af[0].y*as[0].y);
    float2 w2 = make_float2(af[1].x*as[1].x, af[1].y*as[1].y);
    float2 w3 = make_float2(af[2].x*as[2].x, af[2].y*as[2].y);
    float2 w4 = make_float2(af[3].x*as[3].x, af[3].y*as[3].y);

    float2 x0e = *(const float2*)(sx + 2*lane);
    float2 v01 = *(const float2*)(sx + 128 + 6*lane);
    float2 v23 = *(const float2*)(sx + 128 + 6*lane + 2);
    float2 v45 = *(const float2*)(sx + 128 + 6*lane + 4);

    float dotA = v01.x*sh.y + v01.y*sh.z + v23.x*sh.w;
    float dotB = v23.y*sh.y + v45.x*sh.z + v45.y*sh.w;
    const float is3 = 0.57735026919f;
    o0.x += w1.x*x0e.x*sh.x + w4.x*dotA*is3;
    o0.y += w1.y*x0e.y*sh.x + w4.y*dotB*is3;
    o1a[0] += w2.x*x0e.x*sh.y + w3.x*v01.x*sh.x;
    o1a[1] += w2.x*x0e.x*sh.z + w3.x*v01.y*sh.x;
    o1a[2] += w2.x*x0e.x*sh.w + w3.x*v23.x*sh.x;
    o1b[0] += w2.y*x0e.y*sh.y + w3.y*v23.y*sh.x;
    o1b[1] += w2.y*x0e.y*sh.z + w3.y*v45.x*sh.x;
    o1b[2] += w2.y*x0e.y*sh.w + w3.y*v45.y*sh.x;
}

// ---------------- K4: gather — wave per dst node, fused dual GEMV ----------
__global__ __launch_bounds__(256) void k_edge_out(
    const float* __restrict__ fbuf, const float* __restrict__ sbuf,
    const float* __restrict__ self_x, const float* __restrict__ esh,
    const int* __restrict__ rowptr, const int2* __restrict__ ebuf,
    const float* __restrict__ Wf2, const float* __restrict__ Ws2,
    float* __restrict__ out)
{
    const int tid  = threadIdx.x;
    const int lane = tid & 63;
    const int n    = blockIdx.x * 4 + (tid >> 6);   // wave -> dst node

    // defensive clamps: never trigger with a correct CSR, but bound the loop
    // and all addresses even under poisoned workspace (0xAA...)
    int start = rowptr[n];
    int end   = rowptr[n+1];
    if (start < 0) start = 0;
    if (end > EE)  end = EE;

    // channel pair: u0 = 2*lane, u1 = 2*lane+1  (float2-contiguous everywhere)
    float2 o0 = make_float2(0.f, 0.f);
    float  o1a[3] = {0.f, 0.f, 0.f};
    float  o1b[3] = {0.f, 0.f, 0.f};

    for (int i = start; i < end; i += 2){
        const bool two = (i + 1 < end);
        int2 pA = ebuf[i];
        int2 pB = two ? ebuf[i+1] : pA;
        // mask indices into valid range (no-op for correct data)
        pA.x &= (pA.x >= 0 && pA.x < EE) ? ~0 : 0;
        pA.y &= (pA.y >= 0 && pA.y < NN) ? ~0 : 0;
        pB.x &= (pB.x >= 0 && pB.x < EE) ? ~0 : 0;
        pB.y &= (pB.y >= 0 && pB.y < NN) ? ~0 : 0;

        // lane<32 holds fb[lane]; lane>=32 holds sb[lane-32]
        float rA = (lane < 32) ? fbuf[(size_t)pA.x*32 + lane]
                               : sbuf[(size_t)pA.x*32 + lane - 32];
        float rB = (lane < 32) ? fbuf[(size_t)pB.x*32 + lane]
                               : sbuf[(size_t)pB.x*32 + lane - 32];

        // dot accumulators: af[q]/as[q] per edge, .x = channel u0, .y = u1
        float2 afA[4], asA[4], afB[4], asB[4];
        #pragma unroll
        for (int q = 0; q < 4; ++q){
            afA[q]=make_float2(0.f,0.f); asA[q]=make_float2(0.f,0.f);
            afB[q]=make_float2(0.f,0.f); asB[q]=make_float2(0.f,0.f);
        }

        for (int k = 0; k < 32; ++k){
            float fA = __shfl(rA, k),      sA = __shfl(rA, k + 32);
            float fB = __shfl(rB, k),      sB = __shfl(rB, k + 32);
            const float* wfp = Wf2 + (size_t)k*512 + 2*lane;
            const float* wsp = Ws2 + (size_t)k*512 + 2*lane;
            #pragma unroll
            for (int q = 0; q < 4; ++q){
                float2 wf = *(const float2*)(wfp + q*128);
                float2 ws = *(const float2*)(wsp + q*128);
                afA[q].x += fA*wf.x; afA[q].y += fA*wf.y;
                asA[q].x += sA*ws.x; asA[q].y += sA*ws.y;
                afB[q].x += fB*wf.x; afB[q].y += fB*wf.y;
                asB[q].x += sB*ws.x; asB[q].y += sB*ws.y;
            }
        }

        {
            float4 shA = ((const float4*)esh)[pA.x];
            edge_epilogue(o0, o1a, o1b, afA, asA,
                          self_x + (size_t)pA.y*512, shA, lane);
        }
        if (two){
            float4 shB = ((const float4*)esh)[pB.x];
            edge_epilogue(o0, o1a, o1b, afB, asB,
                          self_x + (size_t)pB.y*512, shB, lane);
        }
    }

    float* op = out + (size_t)n * 512;
    *(float2*)(op + 2*lane)           = o0;
    *(float2*)(op + 128 + 6*lane)     = make_float2(o1a[0], o1a[1]);
    *(float2*)(op + 128 + 6*lane + 2) = make_float2(o1a[2], o1b[0]);
    *(float2*)(op + 128 + 6*lane + 4) = make_float2(o1b[1], o1b[2]);
}

// ---------------- K5: out linear + residual (in-place over d_out) ----------
__global__ __launch_bounds__(256) void k_post(
    const float* __restrict__ self_x, const float* __restrict__ x,
    const float* __restrict__ Wo0, const float* __restrict__ bo0,
    const float* __restrict__ Wo1,
    float* __restrict__ out)
{
    __shared__ float tl[512][8];
    const int tid = threadIdx.x;
    const int n0 = blockIdx.x * 8;

    for (int it = 0; it < 4; ++it){
        int idx = tid + 256*it;
        int node = idx >> 7, o4 = idx & 127;
        float4 a = ((const float4*)(out    + (size_t)(n0+node)*512))[o4];
        float4 b = ((const float4*)(self_x + (size_t)(n0+node)*512))[o4];
        tl[o4*4+0][node]=a.x+b.x; tl[o4*4+1][node]=a.y+b.y;
        tl[o4*4+2][node]=a.z+b.z; tl[o4*4+3][node]=a.w+b.w;
    }
    __syncthreads();

    const int j = tid;
    float acc1[8] = {0,0,0,0,0,0,0,0};
    float acc2[8] = {0,0,0,0,0,0,0,0};
    const int o2 = j + 128;
    const int v2 = o2/3, m2 = o2%3;
    if (j < 128){
        for (int u = 0; u < 128; ++u){
            float w1 = Wo0[u*128 + j];
            float w2 = Wo1[u*128 + v2];
            fma8(acc1, &tl[u][0], w1);
            fma8(acc2, &tl[128 + u*3 + m2][0], w2);
        }
        float b = bo0[j];
        #pragma unroll
        for (int n = 0; n < 8; ++n)
            out[(size_t)(n0+n)*512 + j] = acc1[n] + b + x[(size_t)(n0+n)*512 + j];
    } else {
        const int o1 = j - 128, v1 = o1/3, m1 = o1%3;
        for (int u = 0; u < 128; ++u){
            float w1 = Wo1[u*128 + v1];
            float w2 = Wo1[u*128 + v2];
            fma8(acc1, &tl[128 + u*3 + m1][0], w1);
            fma8(acc2, &tl[128 + u*3 + m2][0], w2);
        }
        #pragma unroll
        for (int n = 0; n < 8; ++n)
            out[(size_t)(n0+n)*512 + j] = acc1[n] + x[(size_t)(n0+n)*512 + j];
    }
    #pragma unroll
    for (int n = 0; n < 8; ++n)
        out[(size_t)(n0+n)*512 + j + 256] = acc2[n] + x[(size_t)(n0+n)*512 + j + 256];
}

// ---------------------------------------------------------------------------
extern "C" void kernel_launch(void* const* d_in, const int* in_sizes, int n_in,
                              void* d_out, int out_size, void* d_ws, size_t ws_size,
                              hipStream_t stream)
{
    const float* x    = (const float*)d_in[0];
    const float* esh  = (const float*)d_in[1];
    const float* ea   = (const float*)d_in[2];
    const int*   eidx = (const int*)  d_in[3];
    const float* Wp0  = (const float*)d_in[4];
    const float* bp0  = (const float*)d_in[5];
    const float* Wp1  = (const float*)d_in[6];
    const float* Wnd0 = (const float*)d_in[7];
    const float* bnd0 = (const float*)d_in[8];
    const float* Wnd1 = (const float*)d_in[9];
    const float* Wg1  = (const float*)d_in[10];
    const float* bg1  = (const float*)d_in[11];
    const float* Wg2  = (const float*)d_in[12];
    const float* bg2  = (const float*)d_in[13];
    const float* Wf1  = (const float*)d_in[14];
    const float* Wf2  = (const float*)d_in[15];
    const float* Ws1  = (const float*)d_in[16];
    const float* Ws2  = (const float*)d_in[17];
    const float* Wo0  = (const float*)d_in[18];
    const float* bo0  = (const float*)d_in[19];
    const float* Wo1  = (const float*)d_in[20];

    float* out  = (float*)d_out;
    float* ws   = (float*)d_ws;
    float* p1   = ws;                              // N*384 (dead after k_edge_pre)
    float* sdst = p1   + (size_t)NN*384;           // N*32
    float* sfx  = sdst + (size_t)NN*32;            // N*512
    float* fbuf = sfx  + (size_t)NN*512;           // E*32
    float* sbuf = fbuf + (size_t)EE*32;            // E*32

    // CSR arrays overlay the dead p1 region (1.84 MB << 30 MB)
    int*  cnt    = (int*)p1;
    int*  rowptr = cnt + NN;          // N+1
    int*  cur    = rowptr + NN + 1;   // N
    int2* ebuf   = (int2*)(cur + NN + 1); // E int2 (byte offset 240008, 8-aligned)

    k_pre     <<<NN/8, 256, 0, stream>>>(x, Wp0, bp0, Wp1, Ws1, p1, sdst);
    k_gate_nd <<<NN/8, 256, 0, stream>>>(x, Wg1, bg1, Wg2, bg2, Wnd0, bnd0, Wnd1, sfx);
    k_edge_pre<<<EE/8, 256, 0, stream>>>(p1, sdst, ea, eidx, Wf1, Ws1, fbuf, sbuf);

    // p1 is now dead — build CSR in its place
    hipMemsetAsync(cnt, 0, (size_t)NN*sizeof(int), stream);
    k_count <<<(EE+255)/256, 256, 0, stream>>>(eidx, cnt);
    k_scan  <<<1, 256, 0, stream>>>(cnt, rowptr, cur);
    k_fill  <<<(EE+255)/256, 256, 0, stream>>>(eidx, cur, ebuf);

    k_edge_out<<<NN/4, 256, 0, stream>>>(fbuf, sbuf, sfx, esh, rowptr, ebuf, Wf2, Ws2, out);
    k_post    <<<NN/8, 256, 0, stream>>>(sfx, x, Wo0, bo0, Wo1, out);
}

// Round 5
// 1327.034 us; speedup vs baseline: 1.2095x; 1.2095x over previous
//
#include <hip/hip_runtime.h>
#include <math.h>

#define NN 20000
#define EE 200000
// MUL=128, D=512, EDGE_ATTR=32, HID=32

__device__ __forceinline__ float sspf(float x){
    float sp = (x > 20.f) ? x : log1pf(expf(x));
    return sp - 0.69314718056f;
}

__device__ __forceinline__ void fma8(float* acc, const float* base, float w){
    const float4 a = ((const float4*)base)[0];
    const float4 b = ((const float4*)base)[1];
    acc[0]+=a.x*w; acc[1]+=a.y*w; acc[2]+=a.z*w; acc[3]+=a.w*w;
    acc[4]+=b.x*w; acc[5]+=b.y*w; acc[6]+=b.z*w; acc[7]+=b.w*w;
}

// ---------------- K1: pre irrep_linear -> p1, sdst (p0 consumed in-LDS) ----
__global__ __launch_bounds__(256) void k_pre(
    const float* __restrict__ x, const float* __restrict__ Wp0,
    const float* __restrict__ bp0, const float* __restrict__ Wp1,
    const float* __restrict__ Ws1,
    float* __restrict__ p1, float* __restrict__ sdst)
{
    __shared__ float xl[512][8];    // transposed [feature][node]
    __shared__ float p0l[8][128];
    const int tid = threadIdx.x;
    const int n0 = blockIdx.x * 8;

    for (int it = 0; it < 4; ++it){
        int idx = tid + 256*it;           // 0..1023 float4 slots
        int node = idx >> 7, o4 = idx & 127;
        float4 v = ((const float4*)(x + (size_t)(n0+node)*512))[o4];
        xl[o4*4+0][node]=v.x; xl[o4*4+1][node]=v.y;
        xl[o4*4+2][node]=v.z; xl[o4*4+3][node]=v.w;
    }
    __syncthreads();

    const int j = tid;
    float acc1[8] = {0,0,0,0,0,0,0,0};
    float acc2[8] = {0,0,0,0,0,0,0,0};
    const int o2 = j + 128;               // p1-index in [128,384)
    const int v2 = o2/3, m2 = o2%3;

    if (j < 128){
        for (int u = 0; u < 128; ++u){
            float w1 = Wp0[u*128 + j];
            float w2 = Wp1[u*128 + v2];
            fma8(acc1, &xl[u][0], w1);
            fma8(acc2, &xl[128 + u*3 + m2][0], w2);
        }
        float b = bp0[j];
        #pragma unroll
        for (int n = 0; n < 8; ++n) p0l[n][j] = acc1[n] + b;
    } else {
        const int o1 = j - 128, v1 = o1/3, m1 = o1%3;
        for (int u = 0; u < 128; ++u){
            float w1 = Wp1[u*128 + v1];
            float w2 = Wp1[u*128 + v2];
            fma8(acc1, &xl[128 + u*3 + m1][0], w1);
            fma8(acc2, &xl[128 + u*3 + m2][0], w2);
        }
        #pragma unroll
        for (int n = 0; n < 8; ++n) p1[(size_t)(n0+n)*384 + (j-128)] = acc1[n];
    }
    #pragma unroll
    for (int n = 0; n < 8; ++n) p1[(size_t)(n0+n)*384 + o2] = acc2[n];
    __syncthreads();

    // sdst = p0 @ (Ws1[0:128] + Ws1[128:256])  (the dst-only part of s0@W_s1)
    {
        int n = tid >> 5, h = tid & 31;
        float s = 0.f;
        for (int u = 0; u < 128; ++u){
            float wc = Ws1[u*32 + h] + Ws1[(128+u)*32 + h];
            s += p0l[n][u] * wc;
        }
        sdst[(size_t)(n0+n)*32 + h] = s;
    }
}

// ---------------- K2: gate + node irrep_linear -> self_x -------------------
__global__ __launch_bounds__(256) void k_gate_nd(
    const float* __restrict__ x,
    const float* __restrict__ Wg1, const float* __restrict__ bg1,
    const float* __restrict__ Wg2, const float* __restrict__ bg2,
    const float* __restrict__ Wnd0, const float* __restrict__ bnd0,
    const float* __restrict__ Wnd1,
    float* __restrict__ self_x)
{
    __shared__ float xl[512][8];
    __shared__ float tl[256][8];   // t, then reused for g
    __shared__ float hl[256][8];
    const int tid = threadIdx.x;
    const int n0 = blockIdx.x * 8;

    for (int it = 0; it < 4; ++it){
        int idx = tid + 256*it;
        int node = idx >> 7, o4 = idx & 127;
        float4 v = ((const float4*)(x + (size_t)(n0+node)*512))[o4];
        xl[o4*4+0][node]=v.x; xl[o4*4+1][node]=v.y;
        xl[o4*4+2][node]=v.z; xl[o4*4+3][node]=v.w;
    }
    __syncthreads();

    { // t = [x0, n1]
        int jj = tid;
        if (jj < 128){
            #pragma unroll
            for (int n = 0; n < 8; ++n) tl[jj][n] = xl[jj][n];
        } else {
            int u = jj - 128;
            #pragma unroll
            for (int n = 0; n < 8; ++n){
                float a = xl[128+u*3][n], b = xl[128+u*3+1][n], c = xl[128+u*3+2][n];
                tl[jj][n] = sqrtf((a*a + b*b + c*c) * (1.f/3.f));
            }
        }
    }
    __syncthreads();

    { // h = silu(t @ Wg1 + bg1)
        float acc[8] = {0,0,0,0,0,0,0,0};
        for (int k = 0; k < 256; ++k){
            float w = Wg1[k*256 + tid];
            fma8(acc, &tl[k][0], w);
        }
        float b = bg1[tid];
        #pragma unroll
        for (int n = 0; n < 8; ++n){
            float v = acc[n] + b;
            hl[tid][n] = v / (1.f + expf(-v));
        }
    }
    __syncthreads();

    { // g = h @ Wg2 + bg2  (stored into tl; tl is dead after the barrier)
        float acc[8] = {0,0,0,0,0,0,0,0};
        for (int k = 0; k < 256; ++k){
            float w = Wg2[k*256 + tid];
            fma8(acc, &hl[k][0], w);
        }
        float b = bg2[tid];
        #pragma unroll
        for (int n = 0; n < 8; ++n) tl[tid][n] = acc[n] + b;
    }
    __syncthreads();

    { // xg in-place into xl
        int jj = tid;
        if (jj < 128){
            #pragma unroll
            for (int n = 0; n < 8; ++n) xl[jj][n] = tl[jj][n];
        } else {
            int u = jj - 128;
            #pragma unroll
            for (int n = 0; n < 8; ++n){
                float g1 = tl[128+u][n];
                xl[128+u*3  ][n] *= g1;
                xl[128+u*3+1][n] *= g1;
                xl[128+u*3+2][n] *= g1;
            }
        }
    }
    __syncthreads();

    // nd irrep_linear
    const int j = tid;
    float acc1[8] = {0,0,0,0,0,0,0,0};
    float acc2[8] = {0,0,0,0,0,0,0,0};
    const int o2 = j + 128;
    const int v2 = o2/3, m2 = o2%3;
    if (j < 128){
        for (int u = 0; u < 128; ++u){
            float w1 = Wnd0[u*128 + j];
            float w2 = Wnd1[u*128 + v2];
            fma8(acc1, &xl[u][0], w1);
            fma8(acc2, &xl[128 + u*3 + m2][0], w2);
        }
        float b = bnd0[j];
        #pragma unroll
        for (int n = 0; n < 8; ++n) self_x[(size_t)(n0+n)*512 + j] = acc1[n] + b;
    } else {
        const int o1 = j - 128, v1 = o1/3, m1 = o1%3;
        for (int u = 0; u < 128; ++u){
            float w1 = Wnd1[u*128 + v1];
            float w2 = Wnd1[u*128 + v2];
            fma8(acc1, &xl[128 + u*3 + m1][0], w1);
            fma8(acc2, &xl[128 + u*3 + m2][0], w2);
        }
        #pragma unroll
        for (int n = 0; n < 8; ++n) self_x[(size_t)(n0+n)*512 + j] = acc1[n];
    }
    #pragma unroll
    for (int n = 0; n < 8; ++n) self_x[(size_t)(n0+n)*512 + j + 256] = acc2[n];
}

// ---------------- K3: edge features -> fbuf, sbuf (E x 32 each) ------------
__global__ __launch_bounds__(256) void k_edge_pre(
    const float* __restrict__ p1g, const float* __restrict__ sdst,
    const float* __restrict__ ea, const int* __restrict__ eidx,
    const float* __restrict__ Wf1, const float* __restrict__ Ws1,
    float* __restrict__ fbuf, float* __restrict__ sbuf)
{
    __shared__ float p1d[8][384], p1s[8][384];
    __shared__ float eal[8][32], sdl[8][32];
    __shared__ float ip1l[8][128];
    __shared__ int il[8][2];
    const int tid = threadIdx.x;
    const long e0 = (long)blockIdx.x * 8;

    if (tid < 16){
        int e = tid & 7;
        il[e][tid>>3] = eidx[(size_t)(tid>>3)*EE + e0 + e];
    }
    __syncthreads();

    for (int e = 0; e < 8; ++e){
        int dst = il[e][0], src = il[e][1];
        if (tid < 96)
            ((float4*)p1d[e])[tid] = ((const float4*)(p1g + (size_t)dst*384))[tid];
        else if (tid < 192)
            ((float4*)p1s[e])[tid-96] = ((const float4*)(p1g + (size_t)src*384))[tid-96];
        else if (tid < 200)
            ((float4*)eal[e])[tid-192] = ((const float4*)(ea + (e0+e)*32))[tid-192];
        else if (tid < 208)
            ((float4*)sdl[e])[tid-200] = ((const float4*)(sdst + (size_t)dst*32))[tid-200];
    }
    __syncthreads();

    for (int it = 0; it < 4; ++it){
        int idx = tid + 256*it;
        int e = idx >> 7, u = idx & 127;
        ip1l[e][u] = (p1d[e][u*3]*p1s[e][u*3] + p1d[e][u*3+1]*p1s[e][u*3+1]
                    + p1d[e][u*3+2]*p1s[e][u*3+2]) * (1.f/3.f);
    }
    __syncthreads();

    {
        int e = tid >> 5, h = tid & 31;
        float f = 0.f;
        for (int k = 0; k < 32; ++k) f += eal[e][k] * Wf1[k*32 + h];
        float s = sdl[e][h];
        for (int u = 0; u < 128; ++u) s += ip1l[e][u] * Ws1[(256+u)*32 + h];
        fbuf[(e0+e)*32 + h] = sspf(f);
        sbuf[(e0+e)*32 + h] = sspf(s);
    }
}

// ---------------- CSR build: count, scan, fill -----------------------------
__global__ __launch_bounds__(256) void k_count(
    const int* __restrict__ eidx, int* __restrict__ cnt)
{
    int e = blockIdx.x * 256 + threadIdx.x;
    if (e < EE){
        int d = eidx[e];
        if (d >= 0 && d < NN) atomicAdd(&cnt[d], 1);
    }
}

__global__ __launch_bounds__(256) void k_scan(
    const int* __restrict__ cnt, int* __restrict__ rowptr, int* __restrict__ cur)
{
    __shared__ int part[256];
    const int t = threadIdx.x;
    const int CHUNK = 79;             // 256*79 = 20224 >= 20000
    const int base = t * CHUNK;
    int s = 0;
    for (int i = 0; i < CHUNK; ++i){
        int idx = base + i;
        if (idx < NN) s += cnt[idx];
    }
    part[t] = s;
    __syncthreads();
    for (int off = 1; off < 256; off <<= 1){
        int v = (t >= off) ? part[t-off] : 0;
        __syncthreads();
        part[t] += v;
        __syncthreads();
    }
    int run = (t == 0) ? 0 : part[t-1];
    for (int i = 0; i < CHUNK; ++i){
        int idx = base + i;
        if (idx < NN){
            rowptr[idx] = run;
            cur[idx]    = run;
            run += cnt[idx];
        }
    }
    if (t == 255) rowptr[NN] = run;
}

__global__ __launch_bounds__(256) void k_fill(
    const int* __restrict__ eidx, int* __restrict__ cur, int2* __restrict__ ebuf)
{
    int e = blockIdx.x * 256 + threadIdx.x;
    if (e < EE){
        int dst = eidx[e];
        int src = eidx[EE + e];
        if (dst >= 0 && dst < NN){
            int pos = atomicAdd(&cur[dst], 1);
            if (pos >= 0 && pos < EE) ebuf[pos] = make_int2(e, src);
        }
    }
}

// ---------------- K4 epilogue: apply one edge's weights --------------------
__device__ __forceinline__ void edge_epilogue(
    float2& o0, float* o1a, float* o1b,
    const float2 af[4], const float2 as[4], float msk,
    const float* __restrict__ sx, float4 sh, int lane)
{
    float2 w1 = make_float2(af[0].x*as[0].x*msk, af[0].y*as[0].y*msk);
    float2 w2 = make_float2(af[1].x*as[1].x*msk, af[1].y*as[1].y*msk);
    float2 w3 = make_float2(af[2].x*as[2].x*msk, af[2].y*as[2].y*msk);
    float2 w4 = make_float2(af[3].x*as[3].x*msk, af[3].y*as[3].y*msk);

    float2 x0e = *(const float2*)(sx + 2*lane);
    float2 v01 = *(const float2*)(sx + 128 + 6*lane);
    float2 v23 = *(const float2*)(sx + 128 + 6*lane + 2);
    float2 v45 = *(const float2*)(sx + 128 + 6*lane + 4);

    float dotA = v01.x*sh.y + v01.y*sh.z + v23.x*sh.w;
    float dotB = v23.y*sh.y + v45.x*sh.z + v45.y*sh.w;
    const float is3 = 0.57735026919f;
    o0.x += w1.x*x0e.x*sh.x + w4.x*dotA*is3;
    o0.y += w1.y*x0e.y*sh.x + w4.y*dotB*is3;
    o1a[0] += w2.x*x0e.x*sh.y + w3.x*v01.x*sh.x;
    o1a[1] += w2.x*x0e.x*sh.z + w3.x*v01.y*sh.x;
    o1a[2] += w2.x*x0e.x*sh.w + w3.x*v23.x*sh.x;
    o1b[0] += w2.y*x0e.y*sh.y + w3.y*v23.y*sh.x;
    o1b[1] += w2.y*x0e.y*sh.z + w3.y*v45.x*sh.x;
    o1b[2] += w2.y*x0e.y*sh.w + w3.y*v45.y*sh.x;
}

// ---------------- K4: gather — wave per dst node, fused dual GEMV ----------
// 4 edges per k-loop (weight loads amortized 4x), k unrolled 2x for load
// pipelining; tail edges handled by mask-scaling (msk=0 zeroes contribution).
__global__ __launch_bounds__(256) void k_edge_out(
    const float* __restrict__ fbuf, const float* __restrict__ sbuf,
    const float* __restrict__ self_x, const float* __restrict__ esh,
    const int* __restrict__ rowptr, const int2* __restrict__ ebuf,
    const float* __restrict__ Wf2, const float* __restrict__ Ws2,
    float* __restrict__ out)
{
    const int tid  = threadIdx.x;
    const int lane = tid & 63;
    const int n    = blockIdx.x * 4 + (tid >> 6);   // wave -> dst node

    // defensive clamps (no-ops for a correct CSR; bound everything under
    // poisoned workspace)
    int start = rowptr[n];
    int end   = rowptr[n+1];
    if (start < 0) start = 0;
    if (end > EE)  end = EE;

    float2 o0 = make_float2(0.f, 0.f);
    float  o1a[3] = {0.f, 0.f, 0.f};
    float  o1b[3] = {0.f, 0.f, 0.f};

    for (int i = start; i < end; i += 4){
        int2  p[4];
        float msk[4];
        float r[4];
        #pragma unroll
        for (int j = 0; j < 4; ++j){
            int idx = i + j;
            bool valid = (idx < end);
            int2 pe = ebuf[valid ? idx : i];
            // mask indices into valid range (no-op for correct data)
            if (!(pe.x >= 0 && pe.x < EE)) pe.x = 0;
            if (!(pe.y >= 0 && pe.y < NN)) pe.y = 0;
            p[j]   = pe;
            msk[j] = valid ? 1.f : 0.f;
        }
        #pragma unroll
        for (int j = 0; j < 4; ++j){
            // lane<32 holds fb[lane]; lane>=32 holds sb[lane-32]
            r[j] = (lane < 32) ? fbuf[(size_t)p[j].x*32 + lane]
                               : sbuf[(size_t)p[j].x*32 + lane - 32];
        }

        // dot accumulators: af[j][q]/as[j][q], .x = channel 2*lane, .y = +1
        float2 af[4][4], as_[4][4];
        #pragma unroll
        for (int j = 0; j < 4; ++j)
            #pragma unroll
            for (int q = 0; q < 4; ++q){
                af[j][q]  = make_float2(0.f, 0.f);
                as_[j][q] = make_float2(0.f, 0.f);
            }

        #pragma unroll 2
        for (int k = 0; k < 32; ++k){
            float f[4], s[4];
            #pragma unroll
            for (int j = 0; j < 4; ++j){
                f[j] = __shfl(r[j], k);
                s[j] = __shfl(r[j], k + 32);
            }
            const float* wfp = Wf2 + (size_t)k*512 + 2*lane;
            const float* wsp = Ws2 + (size_t)k*512 + 2*lane;
            #pragma unroll
            for (int q = 0; q < 4; ++q){
                float2 wf = *(const float2*)(wfp + q*128);
                float2 ws = *(const float2*)(wsp + q*128);
                #pragma unroll
                for (int j = 0; j < 4; ++j){
                    af[j][q].x  += f[j]*wf.x; af[j][q].y  += f[j]*wf.y;
                    as_[j][q].x += s[j]*ws.x; as_[j][q].y += s[j]*ws.y;
                }
            }
        }

        #pragma unroll
        for (int j = 0; j < 4; ++j){
            float4 sh = ((const float4*)esh)[p[j].x];
            edge_epilogue(o0, o1a, o1b, af[j], as_[j], msk[j],
                          self_x + (size_t)p[j].y*512, sh, lane);
        }
    }

    float* op = out + (size_t)n * 512;
    *(float2*)(op + 2*lane)           = o0;
    *(float2*)(op + 128 + 6*lane)     = make_float2(o1a[0], o1a[1]);
    *(float2*)(op + 128 + 6*lane + 2) = make_float2(o1a[2], o1b[0]);
    *(float2*)(op + 128 + 6*lane + 4) = make_float2(o1b[1], o1b[2]);
}

// ---------------- K5: out linear + residual (in-place over d_out) ----------
__global__ __launch_bounds__(256) void k_post(
    const float* __restrict__ self_x, const float* __restrict__ x,
    const float* __restrict__ Wo0, const float* __restrict__ bo0,
    const float* __restrict__ Wo1,
    float* __restrict__ out)
{
    __shared__ float tl[512][8];
    const int tid = threadIdx.x;
    const int n0 = blockIdx.x * 8;

    for (int it = 0; it < 4; ++it){
        int idx = tid + 256*it;
        int node = idx >> 7, o4 = idx & 127;
        float4 a = ((const float4*)(out    + (size_t)(n0+node)*512))[o4];
        float4 b = ((const float4*)(self_x + (size_t)(n0+node)*512))[o4];
        tl[o4*4+0][node]=a.x+b.x; tl[o4*4+1][node]=a.y+b.y;
        tl[o4*4+2][node]=a.z+b.z; tl[o4*4+3][node]=a.w+b.w;
    }
    __syncthreads();

    const int j = tid;
    float acc1[8] = {0,0,0,0,0,0,0,0};
    float acc2[8] = {0,0,0,0,0,0,0,0};
    const int o2 = j + 128;
    const int v2 = o2/3, m2 = o2%3;
    if (j < 128){
        for (int u = 0; u < 128; ++u){
            float w1 = Wo0[u*128 + j];
            float w2 = Wo1[u*128 + v2];
            fma8(acc1, &tl[u][0], w1);
            fma8(acc2, &tl[128 + u*3 + m2][0], w2);
        }
        float b = bo0[j];
        #pragma unroll
        for (int n = 0; n < 8; ++n)
            out[(size_t)(n0+n)*512 + j] = acc1[n] + b + x[(size_t)(n0+n)*512 + j];
    } else {
        const int o1 = j - 128, v1 = o1/3, m1 = o1%3;
        for (int u = 0; u < 128; ++u){
            float w1 = Wo1[u*128 + v1];
            float w2 = Wo1[u*128 + v2];
            fma8(acc1, &tl[128 + u*3 + m1][0], w1);
            fma8(acc2, &tl[128 + u*3 + m2][0], w2);
        }
        #pragma unroll
        for (int n = 0; n < 8; ++n)
            out[(size_t)(n0+n)*512 + j] = acc1[n] + x[(size_t)(n0+n)*512 + j];
    }
    #pragma unroll
    for (int n = 0; n < 8; ++n)
        out[(size_t)(n0+n)*512 + j + 256] = acc2[n] + x[(size_t)(n0+n)*512 + j + 256];
}

// ---------------------------------------------------------------------------
extern "C" void kernel_launch(void* const* d_in, const int* in_sizes, int n_in,
                              void* d_out, int out_size, void* d_ws, size_t ws_size,
                              hipStream_t stream)
{
    const float* x    = (const float*)d_in[0];
    const float* esh  = (const float*)d_in[1];
    const float* ea   = (const float*)d_in[2];
    const int*   eidx = (const int*)  d_in[3];
    const float* Wp0  = (const float*)d_in[4];
    const float* bp0  = (const float*)d_in[5];
    const float* Wp1  = (const float*)d_in[6];
    const float* Wnd0 = (const float*)d_in[7];
    const float* bnd0 = (const float*)d_in[8];
    const float* Wnd1 = (const float*)d_in[9];
    const float* Wg1  = (const float*)d_in[10];
    const float* bg1  = (const float*)d_in[11];
    const float* Wg2  = (const float*)d_in[12];
    const float* bg2  = (const float*)d_in[13];
    const float* Wf1  = (const float*)d_in[14];
    const float* Wf2  = (const float*)d_in[15];
    const float* Ws1  = (const float*)d_in[16];
    const float* Ws2  = (const float*)d_in[17];
    const float* Wo0  = (const float*)d_in[18];
    const float* bo0  = (const float*)d_in[19];
    const float* Wo1  = (const float*)d_in[20];

    float* out  = (float*)d_out;
    float* ws   = (float*)d_ws;
    float* p1   = ws;                              // N*384 (dead after k_edge_pre)
    float* sdst = p1   + (size_t)NN*384;           // N*32
    float* sfx  = sdst + (size_t)NN*32;            // N*512
    float* fbuf = sfx  + (size_t)NN*512;           // E*32
    float* sbuf = fbuf + (size_t)EE*32;            // E*32

    // CSR arrays overlay the dead p1 region (1.84 MB << 30 MB)
    int*  cnt    = (int*)p1;
    int*  rowptr = cnt + NN;          // N+1
    int*  cur    = rowptr + NN + 1;   // N
    int2* ebuf   = (int2*)(cur + NN + 1); // E int2 (byte offset 240008, 8-aligned)

    k_pre     <<<NN/8, 256, 0, stream>>>(x, Wp0, bp0, Wp1, Ws1, p1, sdst);
    k_gate_nd <<<NN/8, 256, 0, stream>>>(x, Wg1, bg1, Wg2, bg2, Wnd0, bnd0, Wnd1, sfx);
    k_edge_pre<<<EE/8, 256, 0, stream>>>(p1, sdst, ea, eidx, Wf1, Ws1, fbuf, sbuf);

    // p1 is now dead — build CSR in its place
    hipMemsetAsync(cnt, 0, (size_t)NN*sizeof(int), stream);
    k_count <<<(EE+255)/256, 256, 0, stream>>>(eidx, cnt);
    k_scan  <<<1, 256, 0, stream>>>(cnt, rowptr, cur);
    k_fill  <<<(EE+255)/256, 256, 0, stream>>>(eidx, cur, ebuf);

    k_edge_out<<<NN/4, 256, 0, stream>>>(fbuf, sbuf, sfx, esh, rowptr, ebuf, Wf2, Ws2, out);
    k_post    <<<NN/8, 256, 0, stream>>>(sfx, x, Wo0, bo0, Wo1, out);
}

// Round 6
// 1324.445 us; speedup vs baseline: 1.2118x; 1.0020x over previous
//
#include <hip/hip_runtime.h>
#include <hip/hip_fp16.h>
#include <math.h>

#define NN 20000
#define EE 200000
// MUL=128, D=512, EDGE_ATTR=32, HID=32

__device__ __forceinline__ float sspf(float x){
    float sp = (x > 20.f) ? x : log1pf(expf(x));
    return sp - 0.69314718056f;
}

__device__ __forceinline__ void fma8(float* acc, const float* base, float w){
    const float4 a = ((const float4*)base)[0];
    const float4 b = ((const float4*)base)[1];
    acc[0]+=a.x*w; acc[1]+=a.y*w; acc[2]+=a.z*w; acc[3]+=a.w*w;
    acc[4]+=b.x*w; acc[5]+=b.y*w; acc[6]+=b.z*w; acc[7]+=b.w*w;
}

// ---------------- K1: pre irrep_linear -> p1, sdst (p0 consumed in-LDS) ----
__global__ __launch_bounds__(256) void k_pre(
    const float* __restrict__ x, const float* __restrict__ Wp0,
    const float* __restrict__ bp0, const float* __restrict__ Wp1,
    const float* __restrict__ Ws1,
    float* __restrict__ p1, float* __restrict__ sdst)
{
    __shared__ float xl[512][8];    // transposed [feature][node]
    __shared__ float p0l[8][128];
    const int tid = threadIdx.x;
    const int n0 = blockIdx.x * 8;

    for (int it = 0; it < 4; ++it){
        int idx = tid + 256*it;           // 0..1023 float4 slots
        int node = idx >> 7, o4 = idx & 127;
        float4 v = ((const float4*)(x + (size_t)(n0+node)*512))[o4];
        xl[o4*4+0][node]=v.x; xl[o4*4+1][node]=v.y;
        xl[o4*4+2][node]=v.z; xl[o4*4+3][node]=v.w;
    }
    __syncthreads();

    const int j = tid;
    float acc1[8] = {0,0,0,0,0,0,0,0};
    float acc2[8] = {0,0,0,0,0,0,0,0};
    const int o2 = j + 128;               // p1-index in [128,384)
    const int v2 = o2/3, m2 = o2%3;

    if (j < 128){
        for (int u = 0; u < 128; ++u){
            float w1 = Wp0[u*128 + j];
            float w2 = Wp1[u*128 + v2];
            fma8(acc1, &xl[u][0], w1);
            fma8(acc2, &xl[128 + u*3 + m2][0], w2);
        }
        float b = bp0[j];
        #pragma unroll
        for (int n = 0; n < 8; ++n) p0l[n][j] = acc1[n] + b;
    } else {
        const int o1 = j - 128, v1 = o1/3, m1 = o1%3;
        for (int u = 0; u < 128; ++u){
            float w1 = Wp1[u*128 + v1];
            float w2 = Wp1[u*128 + v2];
            fma8(acc1, &xl[128 + u*3 + m1][0], w1);
            fma8(acc2, &xl[128 + u*3 + m2][0], w2);
        }
        #pragma unroll
        for (int n = 0; n < 8; ++n) p1[(size_t)(n0+n)*384 + (j-128)] = acc1[n];
    }
    #pragma unroll
    for (int n = 0; n < 8; ++n) p1[(size_t)(n0+n)*384 + o2] = acc2[n];
    __syncthreads();

    // sdst = p0 @ (Ws1[0:128] + Ws1[128:256])  (the dst-only part of s0@W_s1)
    {
        int n = tid >> 5, h = tid & 31;
        float s = 0.f;
        for (int u = 0; u < 128; ++u){
            float wc = Ws1[u*32 + h] + Ws1[(128+u)*32 + h];
            s += p0l[n][u] * wc;
        }
        sdst[(size_t)(n0+n)*32 + h] = s;
    }
}

// ---------------- K2: gate + node irrep_linear -> self_x -------------------
__global__ __launch_bounds__(256) void k_gate_nd(
    const float* __restrict__ x,
    const float* __restrict__ Wg1, const float* __restrict__ bg1,
    const float* __restrict__ Wg2, const float* __restrict__ bg2,
    const float* __restrict__ Wnd0, const float* __restrict__ bnd0,
    const float* __restrict__ Wnd1,
    float* __restrict__ self_x)
{
    __shared__ float xl[512][8];
    __shared__ float tl[256][8];   // t, then reused for g
    __shared__ float hl[256][8];
    const int tid = threadIdx.x;
    const int n0 = blockIdx.x * 8;

    for (int it = 0; it < 4; ++it){
        int idx = tid + 256*it;
        int node = idx >> 7, o4 = idx & 127;
        float4 v = ((const float4*)(x + (size_t)(n0+node)*512))[o4];
        xl[o4*4+0][node]=v.x; xl[o4*4+1][node]=v.y;
        xl[o4*4+2][node]=v.z; xl[o4*4+3][node]=v.w;
    }
    __syncthreads();

    { // t = [x0, n1]
        int jj = tid;
        if (jj < 128){
            #pragma unroll
            for (int n = 0; n < 8; ++n) tl[jj][n] = xl[jj][n];
        } else {
            int u = jj - 128;
            #pragma unroll
            for (int n = 0; n < 8; ++n){
                float a = xl[128+u*3][n], b = xl[128+u*3+1][n], c = xl[128+u*3+2][n];
                tl[jj][n] = sqrtf((a*a + b*b + c*c) * (1.f/3.f));
            }
        }
    }
    __syncthreads();

    { // h = silu(t @ Wg1 + bg1)
        float acc[8] = {0,0,0,0,0,0,0,0};
        for (int k = 0; k < 256; ++k){
            float w = Wg1[k*256 + tid];
            fma8(acc, &tl[k][0], w);
        }
        float b = bg1[tid];
        #pragma unroll
        for (int n = 0; n < 8; ++n){
            float v = acc[n] + b;
            hl[tid][n] = v / (1.f + expf(-v));
        }
    }
    __syncthreads();

    { // g = h @ Wg2 + bg2  (stored into tl; tl is dead after the barrier)
        float acc[8] = {0,0,0,0,0,0,0,0};
        for (int k = 0; k < 256; ++k){
            float w = Wg2[k*256 + tid];
            fma8(acc, &hl[k][0], w);
        }
        float b = bg2[tid];
        #pragma unroll
        for (int n = 0; n < 8; ++n) tl[tid][n] = acc[n] + b;
    }
    __syncthreads();

    { // xg in-place into xl
        int jj = tid;
        if (jj < 128){
            #pragma unroll
            for (int n = 0; n < 8; ++n) xl[jj][n] = tl[jj][n];
        } else {
            int u = jj - 128;
            #pragma unroll
            for (int n = 0; n < 8; ++n){
                float g1 = tl[128+u][n];
                xl[128+u*3  ][n] *= g1;
                xl[128+u*3+1][n] *= g1;
                xl[128+u*3+2][n] *= g1;
            }
        }
    }
    __syncthreads();

    // nd irrep_linear
    const int j = tid;
    float acc1[8] = {0,0,0,0,0,0,0,0};
    float acc2[8] = {0,0,0,0,0,0,0,0};
    const int o2 = j + 128;
    const int v2 = o2/3, m2 = o2%3;
    if (j < 128){
        for (int u = 0; u < 128; ++u){
            float w1 = Wnd0[u*128 + j];
            float w2 = Wnd1[u*128 + v2];
            fma8(acc1, &xl[u][0], w1);
            fma8(acc2, &xl[128 + u*3 + m2][0], w2);
        }
        float b = bnd0[j];
        #pragma unroll
        for (int n = 0; n < 8; ++n) self_x[(size_t)(n0+n)*512 + j] = acc1[n] + b;
    } else {
        const int o1 = j - 128, v1 = o1/3, m1 = o1%3;
        for (int u = 0; u < 128; ++u){
            float w1 = Wnd1[u*128 + v1];
            float w2 = Wnd1[u*128 + v2];
            fma8(acc1, &xl[128 + u*3 + m1][0], w1);
            fma8(acc2, &xl[128 + u*3 + m2][0], w2);
        }
        #pragma unroll
        for (int n = 0; n < 8; ++n) self_x[(size_t)(n0+n)*512 + j] = acc1[n];
    }
    #pragma unroll
    for (int n = 0; n < 8; ++n) self_x[(size_t)(n0+n)*512 + j + 256] = acc2[n];
}

// ---------------- K3: edge features -> fbuf, sbuf (E x 32 each) ------------
__global__ __launch_bounds__(256) void k_edge_pre(
    const float* __restrict__ p1g, const float* __restrict__ sdst,
    const float* __restrict__ ea, const int* __restrict__ eidx,
    const float* __restrict__ Wf1, const float* __restrict__ Ws1,
    float* __restrict__ fbuf, float* __restrict__ sbuf)
{
    __shared__ float p1d[8][384], p1s[8][384];
    __shared__ float eal[8][32], sdl[8][32];
    __shared__ float ip1l[8][128];
    __shared__ int il[8][2];
    const int tid = threadIdx.x;
    const long e0 = (long)blockIdx.x * 8;

    if (tid < 16){
        int e = tid & 7;
        il[e][tid>>3] = eidx[(size_t)(tid>>3)*EE + e0 + e];
    }
    __syncthreads();

    for (int e = 0; e < 8; ++e){
        int dst = il[e][0], src = il[e][1];
        if (tid < 96)
            ((float4*)p1d[e])[tid] = ((const float4*)(p1g + (size_t)dst*384))[tid];
        else if (tid < 192)
            ((float4*)p1s[e])[tid-96] = ((const float4*)(p1g + (size_t)src*384))[tid-96];
        else if (tid < 200)
            ((float4*)eal[e])[tid-192] = ((const float4*)(ea + (e0+e)*32))[tid-192];
        else if (tid < 208)
            ((float4*)sdl[e])[tid-200] = ((const float4*)(sdst + (size_t)dst*32))[tid-200];
    }
    __syncthreads();

    for (int it = 0; it < 4; ++it){
        int idx = tid + 256*it;
        int e = idx >> 7, u = idx & 127;
        ip1l[e][u] = (p1d[e][u*3]*p1s[e][u*3] + p1d[e][u*3+1]*p1s[e][u*3+1]
                    + p1d[e][u*3+2]*p1s[e][u*3+2]) * (1.f/3.f);
    }
    __syncthreads();

    {
        int e = tid >> 5, h = tid & 31;
        float f = 0.f;
        for (int k = 0; k < 32; ++k) f += eal[e][k] * Wf1[k*32 + h];
        float s = sdl[e][h];
        for (int u = 0; u < 128; ++u) s += ip1l[e][u] * Ws1[(256+u)*32 + h];
        fbuf[(e0+e)*32 + h] = sspf(f);
        sbuf[(e0+e)*32 + h] = sspf(s);
    }
}

// ---------------- CSR build: count, scan, fill -----------------------------
__global__ __launch_bounds__(256) void k_count(
    const int* __restrict__ eidx, int* __restrict__ cnt)
{
    int e = blockIdx.x * 256 + threadIdx.x;
    if (e < EE){
        int d = eidx[e];
        if (d >= 0 && d < NN) atomicAdd(&cnt[d], 1);
    }
}

__global__ __launch_bounds__(256) void k_scan(
    const int* __restrict__ cnt, int* __restrict__ rowptr, int* __restrict__ cur)
{
    __shared__ int part[256];
    const int t = threadIdx.x;
    const int CHUNK = 79;             // 256*79 = 20224 >= 20000
    const int base = t * CHUNK;
    int s = 0;
    for (int i = 0; i < CHUNK; ++i){
        int idx = base + i;
        if (idx < NN) s += cnt[idx];
    }
    part[t] = s;
    __syncthreads();
    for (int off = 1; off < 256; off <<= 1){
        int v = (t >= off) ? part[t-off] : 0;
        __syncthreads();
        part[t] += v;
        __syncthreads();
    }
    int run = (t == 0) ? 0 : part[t-1];
    for (int i = 0; i < CHUNK; ++i){
        int idx = base + i;
        if (idx < NN){
            rowptr[idx] = run;
            cur[idx]    = run;
            run += cnt[idx];
        }
    }
    if (t == 255) rowptr[NN] = run;
}

__global__ __launch_bounds__(256) void k_fill(
    const int* __restrict__ eidx, int* __restrict__ cur, int2* __restrict__ ebuf)
{
    int e = blockIdx.x * 256 + threadIdx.x;
    if (e < EE){
        int dst = eidx[e];
        int src = eidx[EE + e];
        if (dst >= 0 && dst < NN){
            int pos = atomicAdd(&cur[dst], 1);
            if (pos >= 0 && pos < EE) ebuf[pos] = make_int2(e, src);
        }
    }
}

// ---------------- fast path A: edge GEMM -> fp16 edge_feat -----------------
// Block = 64 CSR-ordered edges. lanes = edges; wave wv owns channel strip
// [32*wv, 32*wv+32). Weights read via wave-uniform addresses (scalar loads).
__device__ __forceinline__ void qdot(
    const float* __restrict__ W2f, const float* __restrict__ W2s,
    const float (*fbl)[33], const float (*sbl)[33],
    int lane, int q, int wv, float* wout /*32*/)
{
    float F[32], S[32];
    #pragma unroll
    for (int c = 0; c < 32; ++c){ F[c] = 0.f; S[c] = 0.f; }
    const float* wfp = W2f + q*128 + wv*32;
    const float* wsp = W2s + q*128 + wv*32;
    for (int k = 0; k < 32; ++k){
        float fb = fbl[lane][k];
        float sb = sbl[lane][k];
        const float* wf = wfp + (size_t)k*512;
        const float* ws = wsp + (size_t)k*512;
        #pragma unroll
        for (int c = 0; c < 32; ++c){
            F[c] += fb * wf[c];
            S[c] += sb * ws[c];
        }
    }
    #pragma unroll
    for (int c = 0; c < 32; ++c) wout[c] = F[c] * S[c];
}

__global__ __launch_bounds__(256) void k_w_edge(
    const float* __restrict__ fbuf, const float* __restrict__ sbuf,
    const float* __restrict__ self_x, const float* __restrict__ esh,
    const int2* __restrict__ ebuf,
    const float* __restrict__ Wf2, const float* __restrict__ Ws2,
    __half* __restrict__ ef)
{
    __shared__ int2  il[64];
    __shared__ float fbl[64][33];   // +1 pad: conflict-free lane-spread reads
    __shared__ float sbl[64][33];

    const int tid  = threadIdx.x;
    const int lane = tid & 63;
    const int wv   = __builtin_amdgcn_readfirstlane(tid >> 6); // uniform strip id
    const long e0  = (long)blockIdx.x * 64;

    if (tid < 64){
        int2 pe = ebuf[e0 + tid];
        if (!(pe.x >= 0 && pe.x < EE)) pe.x = 0;   // defensive (poison-safe)
        if (!(pe.y >= 0 && pe.y < NN)) pe.y = 0;
        il[tid] = pe;
    }
    __syncthreads();

    for (int it = 0; it < 8; ++it){
        int idx = tid + 256*it;      // 0..2047
        int e = idx >> 5, k = idx & 31;
        int eid = il[e].x;
        fbl[e][k] = fbuf[(size_t)eid*32 + k];
        sbl[e][k] = sbuf[(size_t)eid*32 + k];
    }
    __syncthreads();

    const int eid = il[lane].x;
    const int src = il[lane].y;
    const float4 sh = ((const float4*)esh)[eid];
    const float* sx = self_x + (size_t)src * 512;
    __half* efr = ef + (size_t)(e0 + lane) * 512;
    const float IS3 = 0.57735026919f;

    float w1r[32], w4r[32];
    qdot(Wf2, Ws2, fbl, sbl, lane, 0, wv, w1r);
    qdot(Wf2, Ws2, fbl, sbl, lane, 3, wv, w4r);

    // epilogue A: out0 channels [32wv, 32wv+32)
    #pragma unroll
    for (int c4 = 0; c4 < 8; ++c4){
        const int cb = wv*32 + c4*4;       // global channel base
        float4 x0 = *(const float4*)(sx + cb);
        float4 xa = *(const float4*)(sx + 128 + 3*cb);
        float4 xb = *(const float4*)(sx + 128 + 3*cb + 4);
        float4 xc = *(const float4*)(sx + 128 + 3*cb + 8);
        float d0 = xa.x*sh.y + xa.y*sh.z + xa.z*sh.w;
        float d1 = xa.w*sh.y + xb.x*sh.z + xb.y*sh.w;
        float d2 = xb.z*sh.y + xb.w*sh.z + xc.x*sh.w;
        float d3 = xc.y*sh.y + xc.z*sh.z + xc.w*sh.w;
        int i0 = c4*4;
        float o0 = w1r[i0+0]*x0.x*sh.x + w4r[i0+0]*d0*IS3;
        float o1 = w1r[i0+1]*x0.y*sh.x + w4r[i0+1]*d1*IS3;
        float o2 = w1r[i0+2]*x0.z*sh.x + w4r[i0+2]*d2*IS3;
        float o3 = w1r[i0+3]*x0.w*sh.x + w4r[i0+3]*d3*IS3;
        __half2* ep = (__half2*)(efr + cb);
        ep[0] = __floats2half2_rn(o0, o1);
        ep[1] = __floats2half2_rn(o2, o3);
    }

    float w2r[32], w3r[32];
    qdot(Wf2, Ws2, fbl, sbl, lane, 1, wv, w2r);
    qdot(Wf2, Ws2, fbl, sbl, lane, 2, wv, w3r);

    // epilogue B: out1 channels -> positions 128+3c+m
    #pragma unroll
    for (int c4 = 0; c4 < 8; ++c4){
        const int cb = wv*32 + c4*4;
        float4 x0 = *(const float4*)(sx + cb);
        float4 xa = *(const float4*)(sx + 128 + 3*cb);
        float4 xb = *(const float4*)(sx + 128 + 3*cb + 4);
        float4 xc = *(const float4*)(sx + 128 + 3*cb + 8);
        int i0 = c4*4;
        float t0 = w2r[i0+0]*x0.x, g0 = w3r[i0+0]*sh.x;
        float t1 = w2r[i0+1]*x0.y, g1 = w3r[i0+1]*sh.x;
        float t2 = w2r[i0+2]*x0.z, g2 = w3r[i0+2]*sh.x;
        float t3 = w2r[i0+3]*x0.w, g3 = w3r[i0+3]*sh.x;
        float m00 = t0*sh.y + g0*xa.x, m01 = t0*sh.z + g0*xa.y, m02 = t0*sh.w + g0*xa.z;
        float m10 = t1*sh.y + g1*xa.w, m11 = t1*sh.z + g1*xb.x, m12 = t1*sh.w + g1*xb.y;
        float m20 = t2*sh.y + g2*xb.z, m21 = t2*sh.z + g2*xb.w, m22 = t2*sh.w + g2*xc.x;
        float m30 = t3*sh.y + g3*xc.y, m31 = t3*sh.z + g3*xc.z, m32 = t3*sh.w + g3*xc.w;
        __half2* ep = (__half2*)(efr + 128 + 3*cb);
        ep[0] = __floats2half2_rn(m00, m01);
        ep[1] = __floats2half2_rn(m02, m10);
        ep[2] = __floats2half2_rn(m11, m12);
        ep[3] = __floats2half2_rn(m20, m21);
        ep[4] = __floats2half2_rn(m22, m30);
        ep[5] = __floats2half2_rn(m31, m32);
    }
}

// ---------------- fast path B: coalesced CSR segment sum -------------------
__global__ __launch_bounds__(256) void k_seg_sum(
    const __half* __restrict__ ef, const int* __restrict__ rowptr,
    float* __restrict__ out)
{
    const int tid  = threadIdx.x;
    const int lane = tid & 63;
    const int n    = blockIdx.x * 4 + (tid >> 6);
    int start = rowptr[n];
    int end   = rowptr[n+1];
    if (start < 0) start = 0;
    if (end > EE)  end = EE;

    float a[8] = {0,0,0,0,0,0,0,0};
    for (int i = start; i < end; ++i){
        float4 rv = *(const float4*)(ef + (size_t)i*512 + lane*8);  // 8 halves
        const __half2* hp = (const __half2*)&rv;
        #pragma unroll
        for (int q = 0; q < 4; ++q){
            float2 f = __half22float2(hp[q]);
            a[2*q]   += f.x;
            a[2*q+1] += f.y;
        }
    }
    float* op = out + (size_t)n*512 + lane*8;
    *(float4*)op       = make_float4(a[0], a[1], a[2], a[3]);
    *((float4*)op + 1) = make_float4(a[4], a[5], a[6], a[7]);
}

// ---------------- fallback K4 (round-5): wave-per-node dual GEMV -----------
__device__ __forceinline__ void edge_epilogue(
    float2& o0, float* o1a, float* o1b,
    const float2 af[4], const float2 as[4], float msk,
    const float* __restrict__ sx, float4 sh, int lane)
{
    float2 w1 = make_float2(af[0].x*as[0].x*msk, af[0].y*as[0].y*msk);
    float2 w2 = make_float2(af[1].x*as[1].x*msk, af[1].y*as[1].y*msk);
    float2 w3 = make_float2(af[2].x*as[2].x*msk, af[2].y*as[2].y*msk);
    float2 w4 = make_float2(af[3].x*as[3].x*msk, af[3].y*as[3].y*msk);

    float2 x0e = *(const float2*)(sx + 2*lane);
    float2 v01 = *(const float2*)(sx + 128 + 6*lane);
    float2 v23 = *(const float2*)(sx + 128 + 6*lane + 2);
    float2 v45 = *(const float2*)(sx + 128 + 6*lane + 4);

    float dotA = v01.x*sh.y + v01.y*sh.z + v23.x*sh.w;
    float dotB = v23.y*sh.y + v45.x*sh.z + v45.y*sh.w;
    const float is3 = 0.57735026919f;
    o0.x += w1.x*x0e.x*sh.x + w4.x*dotA*is3;
    o0.y += w1.y*x0e.y*sh.x + w4.y*dotB*is3;
    o1a[0] += w2.x*x0e.x*sh.y + w3.x*v01.x*sh.x;
    o1a[1] += w2.x*x0e.x*sh.z + w3.x*v01.y*sh.x;
    o1a[2] += w2.x*x0e.x*sh.w + w3.x*v23.x*sh.x;
    o1b[0] += w2.y*x0e.y*sh.y + w3.y*v23.y*sh.x;
    o1b[1] += w2.y*x0e.y*sh.z + w3.y*v45.x*sh.x;
    o1b[2] += w2.y*x0e.y*sh.w + w3.y*v45.y*sh.x;
}

__global__ __launch_bounds__(256) void k_edge_out(
    const float* __restrict__ fbuf, const float* __restrict__ sbuf,
    const float* __restrict__ self_x, const float* __restrict__ esh,
    const int* __restrict__ rowptr, const int2* __restrict__ ebuf,
    const float* __restrict__ Wf2, const float* __restrict__ Ws2,
    float* __restrict__ out)
{
    const int tid  = threadIdx.x;
    const int lane = tid & 63;
    const int n    = blockIdx.x * 4 + (tid >> 6);

    int start = rowptr[n];
    int end   = rowptr[n+1];
    if (start < 0) start = 0;
    if (end > EE)  end = EE;

    float2 o0 = make_float2(0.f, 0.f);
    float  o1a[3] = {0.f, 0.f, 0.f};
    float  o1b[3] = {0.f, 0.f, 0.f};

    for (int i = start; i < end; i += 4){
        int2  p[4];
        float msk[4];
        float r[4];
        #pragma unroll
        for (int j = 0; j < 4; ++j){
            int idx = i + j;
            bool valid = (idx < end);
            int2 pe = ebuf[valid ? idx : i];
            if (!(pe.x >= 0 && pe.x < EE)) pe.x = 0;
            if (!(pe.y >= 0 && pe.y < NN)) pe.y = 0;
            p[j]   = pe;
            msk[j] = valid ? 1.f : 0.f;
        }
        #pragma unroll
        for (int j = 0; j < 4; ++j){
            r[j] = (lane < 32) ? fbuf[(size_t)p[j].x*32 + lane]
                               : sbuf[(size_t)p[j].x*32 + lane - 32];
        }

        float2 af[4][4], as_[4][4];
        #pragma unroll
        for (int j = 0; j < 4; ++j)
            #pragma unroll
            for (int q = 0; q < 4; ++q){
                af[j][q]  = make_float2(0.f, 0.f);
                as_[j][q] = make_float2(0.f, 0.f);
            }

        #pragma unroll 2
        for (int k = 0; k < 32; ++k){
            float f[4], s[4];
            #pragma unroll
            for (int j = 0; j < 4; ++j){
                f[j] = __shfl(r[j], k);
                s[j] = __shfl(r[j], k + 32);
            }
            const float* wfp = Wf2 + (size_t)k*512 + 2*lane;
            const float* wsp = Ws2 + (size_t)k*512 + 2*lane;
            #pragma unroll
            for (int q = 0; q < 4; ++q){
                float2 wf = *(const float2*)(wfp + q*128);
                float2 ws = *(const float2*)(wsp + q*128);
                #pragma unroll
                for (int j = 0; j < 4; ++j){
                    af[j][q].x  += f[j]*wf.x; af[j][q].y  += f[j]*wf.y;
                    as_[j][q].x += s[j]*ws.x; as_[j][q].y += s[j]*ws.y;
                }
            }
        }

        #pragma unroll
        for (int j = 0; j < 4; ++j){
            float4 sh = ((const float4*)esh)[p[j].x];
            edge_epilogue(o0, o1a, o1b, af[j], as_[j], msk[j],
                          self_x + (size_t)p[j].y*512, sh, lane);
        }
    }

    float* op = out + (size_t)n * 512;
    *(float2*)(op + 2*lane)           = o0;
    *(float2*)(op + 128 + 6*lane)     = make_float2(o1a[0], o1a[1]);
    *(float2*)(op + 128 + 6*lane + 2) = make_float2(o1a[2], o1b[0]);
    *(float2*)(op + 128 + 6*lane + 4) = make_float2(o1b[1], o1b[2]);
}

// ---------------- K5: out linear + residual (in-place over d_out) ----------
__global__ __launch_bounds__(256) void k_post(
    const float* __restrict__ self_x, const float* __restrict__ x,
    const float* __restrict__ Wo0, const float* __restrict__ bo0,
    const float* __restrict__ Wo1,
    float* __restrict__ out)
{
    __shared__ float tl[512][8];
    const int tid = threadIdx.x;
    const int n0 = blockIdx.x * 8;

    for (int it = 0; it < 4; ++it){
        int idx = tid + 256*it;
        int node = idx >> 7, o4 = idx & 127;
        float4 a = ((const float4*)(out    + (size_t)(n0+node)*512))[o4];
        float4 b = ((const float4*)(self_x + (size_t)(n0+node)*512))[o4];
        tl[o4*4+0][node]=a.x+b.x; tl[o4*4+1][node]=a.y+b.y;
        tl[o4*4+2][node]=a.z+b.z; tl[o4*4+3][node]=a.w+b.w;
    }
    __syncthreads();

    const int j = tid;
    float acc1[8] = {0,0,0,0,0,0,0,0};
    float acc2[8] = {0,0,0,0,0,0,0,0};
    const int o2 = j + 128;
    const int v2 = o2/3, m2 = o2%3;
    if (j < 128){
        for (int u = 0; u < 128; ++u){
            float w1 = Wo0[u*128 + j];
            float w2 = Wo1[u*128 + v2];
            fma8(acc1, &tl[u][0], w1);
            fma8(acc2, &tl[128 + u*3 + m2][0], w2);
        }
        float b = bo0[j];
        #pragma unroll
        for (int n = 0; n < 8; ++n)
            out[(size_t)(n0+n)*512 + j] = acc1[n] + b + x[(size_t)(n0+n)*512 + j];
    } else {
        const int o1 = j - 128, v1 = o1/3, m1 = o1%3;
        for (int u = 0; u < 128; ++u){
            float w1 = Wo1[u*128 + v1];
            float w2 = Wo1[u*128 + v2];
            fma8(acc1, &tl[128 + u*3 + m1][0], w1);
            fma8(acc2, &tl[128 + u*3 + m2][0], w2);
        }
        #pragma unroll
        for (int n = 0; n < 8; ++n)
            out[(size_t)(n0+n)*512 + j] = acc1[n] + x[(size_t)(n0+n)*512 + j];
    }
    #pragma unroll
    for (int n = 0; n < 8; ++n)
        out[(size_t)(n0+n)*512 + j + 256] = acc2[n] + x[(size_t)(n0+n)*512 + j + 256];
}

// ---------------------------------------------------------------------------
extern "C" void kernel_launch(void* const* d_in, const int* in_sizes, int n_in,
                              void* d_out, int out_size, void* d_ws, size_t ws_size,
                              hipStream_t stream)
{
    const float* x    = (const float*)d_in[0];
    const float* esh  = (const float*)d_in[1];
    const float* ea   = (const float*)d_in[2];
    const int*   eidx = (const int*)  d_in[3];
    const float* Wp0  = (const float*)d_in[4];
    const float* bp0  = (const float*)d_in[5];
    const float* Wp1  = (const float*)d_in[6];
    const float* Wnd0 = (const float*)d_in[7];
    const float* bnd0 = (const float*)d_in[8];
    const float* Wnd1 = (const float*)d_in[9];
    const float* Wg1  = (const float*)d_in[10];
    const float* bg1  = (const float*)d_in[11];
    const float* Wg2  = (const float*)d_in[12];
    const float* bg2  = (const float*)d_in[13];
    const float* Wf1  = (const float*)d_in[14];
    const float* Wf2  = (const float*)d_in[15];
    const float* Ws1  = (const float*)d_in[16];
    const float* Ws2  = (const float*)d_in[17];
    const float* Wo0  = (const float*)d_in[18];
    const float* bo0  = (const float*)d_in[19];
    const float* Wo1  = (const float*)d_in[20];

    float* out  = (float*)d_out;
    float* ws   = (float*)d_ws;
    float* p1   = ws;                              // N*384 (dead after k_edge_pre)
    float* sdst = p1   + (size_t)NN*384;           // N*32
    float* sfx  = sdst + (size_t)NN*32;            // N*512
    float* fbuf = sfx  + (size_t)NN*512;           // E*32
    float* sbuf = fbuf + (size_t)EE*32;            // E*32
    __half* ef  = (__half*)(sbuf + (size_t)EE*32); // E*512 fp16 (fast path only)

    // CSR arrays overlay the dead p1 region (1.84 MB << 30 MB)
    int*  cnt    = (int*)p1;
    int*  rowptr = cnt + NN;          // N+1
    int*  cur    = rowptr + NN + 1;   // N
    int2* ebuf   = (int2*)(cur + NN + 1); // E int2 (byte offset 240008, 8-aligned)

    // fast path needs 125.44 MB (above) + 204.8 MB fp16 edge_feat
    const size_t NEED = (size_t)(NN)*928*4 + (size_t)EE*64*4 + (size_t)EE*512*2;
    const bool fast = (ws_size >= NEED);

    k_pre     <<<NN/8, 256, 0, stream>>>(x, Wp0, bp0, Wp1, Ws1, p1, sdst);
    k_gate_nd <<<NN/8, 256, 0, stream>>>(x, Wg1, bg1, Wg2, bg2, Wnd0, bnd0, Wnd1, sfx);
    k_edge_pre<<<EE/8, 256, 0, stream>>>(p1, sdst, ea, eidx, Wf1, Ws1, fbuf, sbuf);

    // p1 is now dead — build CSR in its place
    hipMemsetAsync(cnt, 0, (size_t)NN*sizeof(int), stream);
    k_count <<<(EE+255)/256, 256, 0, stream>>>(eidx, cnt);
    k_scan  <<<1, 256, 0, stream>>>(cnt, rowptr, cur);
    k_fill  <<<(EE+255)/256, 256, 0, stream>>>(eidx, cur, ebuf);

    if (fast){
        k_w_edge  <<<EE/64, 256, 0, stream>>>(fbuf, sbuf, sfx, esh, ebuf, Wf2, Ws2, ef);
        k_seg_sum <<<NN/4, 256, 0, stream>>>(ef, rowptr, out);
    } else {
        k_edge_out<<<NN/4, 256, 0, stream>>>(fbuf, sbuf, sfx, esh, rowptr, ebuf, Wf2, Ws2, out);
    }
    k_post    <<<NN/8, 256, 0, stream>>>(sfx, x, Wo0, bo0, Wo1, out);
}